// Round 13
// baseline (631.061 us; speedup 1.0000x reference)
//
#include <hip/hip_runtime.h>
#include <math.h>

#define NB 32
#define NL 4096
#define ND 1024
#define NK 64
#define NSPLIT 16

typedef __bf16 bf16_t;
typedef __bf16 bf16x8 __attribute__((ext_vector_type(8)));
typedef __bf16 bf16x4 __attribute__((ext_vector_type(4)));
typedef float f32x4_t __attribute__((ext_vector_type(4)));

__device__ __forceinline__ unsigned short bfbits(float x) {
    bf16_t h = (bf16_t)x;
    return __builtin_bit_cast(unsigned short, h);
}

// ---------------- Kernel 0: W fp32 -> bf16
__global__ __launch_bounds__(256) void k_convw(const float* __restrict__ W,
                                               bf16_t* __restrict__ Wb) {
    const int i = (blockIdx.x * 256 + threadIdx.x) * 4;
    const float4 v = *(const float4*)(W + i);
    bf16x4 o;
    o[0] = (bf16_t)v.x; o[1] = (bf16_t)v.y; o[2] = (bf16_t)v.z; o[3] = (bf16_t)v.w;
    *(bf16x4*)(Wb + i) = o;
}

// ---------------- Fused: logits + online softmax + aggregation (feats read ONCE)
// v2: T14 prefetch of stage half-0 across tiles (pf), early-issue of half-1 (qf)
// under the logits phase, logits loop unroll-4. All index math = round-12 (verified).
__global__ __launch_bounds__(512, 2) void k_fused(const float* __restrict__ feats,
                                                  const bf16_t* __restrict__ Wb,
                                                  const float* __restrict__ bias,
                                                  const int* __restrict__ lens,
                                                  float* __restrict__ pO,
                                                  float* __restrict__ mS,
                                                  float* __restrict__ sS) {
    const int bid = blockIdx.x;
    const int b  = bid >> 4;
    const int sp = bid & 15;
    const int t = threadIdx.x;
    const int w = t >> 6;
    const int lane = t & 63;
    const int lr = lane & 15;
    const int oct = lane >> 4;
    const int len = lens[b];
    const int nT = (len + 63) >> 6;
    const int t0 = (nT * sp) >> 4;
    const int t1 = (nT * (sp + 1)) >> 4;

    extern __shared__ char lds[];
    char*  const fT   = lds;                     // 131072 B
    char*  const lgT  = lds + 131072;            // 16384 B
    float* const red  = (float*)(lds + 147456);  // [64][17]
    float* const mrun = (float*)(lds + 151808);  // [64]
    float* const srun = (float*)(lds + 152064);  // [64]
    float* const mnew = (float*)(lds + 152320);  // [64]
    float* const rA   = (float*)(lds + 152576);  // [64]

    // role constants
    const int mtg = w >> 2, jq = w & 3;          // logits: 2 m-tiles, k-tile jq
    const int kh  = w & 1,  dh = w >> 1;         // agg: k-half, d-quarter
    const int dgrp = (t & 127) * 8;              // stage: 8 d cols
    const int lgq  = t >> 7;                     // stage: l quarter

    const int kA = jq * 16 + lr;                 // logits output k
    const float bs = bias[kA];
    const int kk0 = kh * 32 + lr;                // agg A k base (mt=0)

    if (t < 64) { mrun[t] = -1e30f; srun[t] = 0.f; }

    f32x4_t acc[2][16];
#pragma unroll
    for (int mi = 0; mi < 2; ++mi)
#pragma unroll
        for (int nt = 0; nt < 16; ++nt) acc[mi][nt] = (f32x4_t){0.f, 0.f, 0.f, 0.f};

    float4 pfa0[4], pfa1[4], pfb0[4], pfb1[4];   // stage half-0, cross-tile prefetch
    float4 qfa0[4], qfa1[4], qfb0[4], qfb1[4];   // stage half-1, intra-tile early issue

#define LOADH(tile_, half_, P)                                                        \
    {                                                                                 \
        const int lb_ = (tile_) * 64 + lgq * 16 + (half_) * 8;                        \
        _Pragma("unroll")                                                             \
        for (int lw_ = 0; lw_ < 4; ++lw_) {                                           \
            const float* r0_ = feats + ((size_t)b * NL + lb_ + lw_ * 2) * ND + dgrp;  \
            P##a0[lw_] = *(const float4*)r0_;                                         \
            P##a1[lw_] = *(const float4*)(r0_ + 4);                                   \
            P##b0[lw_] = *(const float4*)(r0_ + ND);                                  \
            P##b1[lw_] = *(const float4*)(r0_ + ND + 4);                              \
        }                                                                             \
    }

#define WRITEH(half_, P)                                                              \
    {                                                                                 \
        const int lbase_ = lgq * 16 + (half_) * 8;                                    \
        unsigned cu[8][4];                                                            \
        _Pragma("unroll")                                                             \
        for (int lw_ = 0; lw_ < 4; ++lw_) {                                           \
            cu[0][lw_] = bfbits(P##a0[lw_].x) | ((unsigned)bfbits(P##b0[lw_].x) << 16); \
            cu[1][lw_] = bfbits(P##a0[lw_].y) | ((unsigned)bfbits(P##b0[lw_].y) << 16); \
            cu[2][lw_] = bfbits(P##a0[lw_].z) | ((unsigned)bfbits(P##b0[lw_].z) << 16); \
            cu[3][lw_] = bfbits(P##a0[lw_].w) | ((unsigned)bfbits(P##b0[lw_].w) << 16); \
            cu[4][lw_] = bfbits(P##a1[lw_].x) | ((unsigned)bfbits(P##b1[lw_].x) << 16); \
            cu[5][lw_] = bfbits(P##a1[lw_].y) | ((unsigned)bfbits(P##b1[lw_].y) << 16); \
            cu[6][lw_] = bfbits(P##a1[lw_].z) | ((unsigned)bfbits(P##b1[lw_].z) << 16); \
            cu[7][lw_] = bfbits(P##a1[lw_].w) | ((unsigned)bfbits(P##b1[lw_].w) << 16); \
        }                                                                             \
        _Pragma("unroll")                                                             \
        for (int j_ = 0; j_ < 8; ++j_) {                                              \
            const int d_ = dgrp + j_;                                                 \
            const int c_ = (lbase_ >> 3) ^ ((d_ ^ (d_ >> 3)) & 7);                    \
            *(uint4*)(fT + d_ * 128 + c_ * 16) =                                      \
                make_uint4(cu[j_][0], cu[j_][1], cu[j_][2], cu[j_][3]);               \
        }                                                                             \
    }

    if (t0 < t1) LOADH(t0, 0, pf);

    for (int tile = t0; tile < t1; ++tile) {
        const int l0 = tile * 64;
        __syncthreads();  // bar0: fT/lgT/red reusable
        WRITEH(0, pf);        // half-0 from prefetched regs
        LOADH(tile, 1, qf);   // issue half-1 loads; land during logits phase

        // ---- LOGITS (verified conv: A m=lr/c=oct*8+j; B n=lr; C col=lr, row=oct*4+r)
        float vals[2][4];
        {
            const float* fp0 = feats + ((size_t)b * NL + l0 + (mtg * 2 + 0) * 16 + lr) * ND + oct * 8;
            const float* fp1 = feats + ((size_t)b * NL + l0 + (mtg * 2 + 1) * 16 + lr) * ND + oct * 8;
            const bf16_t* wr = Wb + (size_t)kA * ND + oct * 8;
            f32x4_t la0 = (f32x4_t){0.f, 0.f, 0.f, 0.f};
            f32x4_t la1 = (f32x4_t){0.f, 0.f, 0.f, 0.f};
#pragma unroll 4
            for (int kk = 0; kk < 32; ++kk) {
                const int d = kk * 32;
                const float4 a0 = *(const float4*)(fp0 + d);
                const float4 a1 = *(const float4*)(fp0 + d + 4);
                const float4 c0 = *(const float4*)(fp1 + d);
                const float4 c1 = *(const float4*)(fp1 + d + 4);
                bf16x8 af0, af1;
                af0[0] = (bf16_t)a0.x; af0[1] = (bf16_t)a0.y; af0[2] = (bf16_t)a0.z; af0[3] = (bf16_t)a0.w;
                af0[4] = (bf16_t)a1.x; af0[5] = (bf16_t)a1.y; af0[6] = (bf16_t)a1.z; af0[7] = (bf16_t)a1.w;
                af1[0] = (bf16_t)c0.x; af1[1] = (bf16_t)c0.y; af1[2] = (bf16_t)c0.z; af1[3] = (bf16_t)c0.w;
                af1[4] = (bf16_t)c1.x; af1[5] = (bf16_t)c1.y; af1[6] = (bf16_t)c1.z; af1[7] = (bf16_t)c1.w;
                const bf16x8 bf = *(const bf16x8*)(wr + d);
                la0 = __builtin_amdgcn_mfma_f32_16x16x32_bf16(af0, bf, la0, 0, 0, 0);
                la1 = __builtin_amdgcn_mfma_f32_16x16x32_bf16(af1, bf, la1, 0, 0, 0);
            }
#pragma unroll
            for (int r = 0; r < 4; ++r) { vals[0][r] = la0[r] + bs; vals[1][r] = la1[r] + bs; }
        }

        WRITEH(1, qf);   // half-1 writes (loads landed under logits)

#pragma unroll
        for (int mi = 0; mi < 2; ++mi) {
            const int mt = mtg * 2 + mi;
            const int c = (mt * 4 + oct) ^ (kA & 15);
            *(float4*)(lgT + kA * 256 + c * 16) =
                make_float4(vals[mi][0], vals[mi][1], vals[mi][2], vals[mi][3]);
            const int lb = l0 + mt * 16 + oct * 4;
            float vm = -1e30f;
#pragma unroll
            for (int r = 0; r < 4; ++r)
                if (lb + r < len) vm = fmaxf(vm, vals[mi][r]);
            red[kA * 17 + mt * 4 + oct] = vm;
        }
        __syncthreads();  // bar1: fT + lgT + red-max ready

        if (t < 64) {
            float mc = red[t * 17];
#pragma unroll
            for (int q = 1; q < 16; ++q) mc = fmaxf(mc, red[t * 17 + q]);
            const float mo = mrun[t];
            const float mn_ = fmaxf(mo, mc);
            mnew[t] = mn_;
            rA[t] = __expf(mo - mn_);
            mrun[t] = mn_;
        }
        __syncthreads();  // bar2: mnew/rA ready

        {
            const float mk = mnew[kA];
#pragma unroll
            for (int mi = 0; mi < 2; ++mi) {
                const int mt = mtg * 2 + mi;
                const int lb = l0 + mt * 16 + oct * 4;
                float sj = 0.f;
#pragma unroll
                for (int r = 0; r < 4; ++r)
                    if (lb + r < len) sj += __expf(vals[mi][r] - mk);
                red[kA * 17 + mt * 4 + oct] = sj;
            }
        }
        __syncthreads();  // bar3: red-s ready

        if (t < 64) {
            float sc_ = 0.f;
#pragma unroll
            for (int q = 0; q < 16; ++q) sc_ += red[t * 17 + q];
            srun[t] = srun[t] * rA[t] + sc_;
        }

        // ---- rescale acc to new basis
        {
            const float4 ra0 = *(const float4*)&rA[kh * 32 + oct * 4];
            const float4 ra1 = *(const float4*)&rA[kh * 32 + 16 + oct * 4];
#pragma unroll
            for (int nt = 0; nt < 16; ++nt) {
                acc[0][nt][0] *= ra0.x; acc[0][nt][1] *= ra0.y;
                acc[0][nt][2] *= ra0.z; acc[0][nt][3] *= ra0.w;
                acc[1][nt][0] *= ra1.x; acc[1][nt][1] *= ra1.y;
                acc[1][nt][2] *= ra1.z; acc[1][nt][3] *= ra1.w;
            }
        }

        // ---- A-frags: p = exp(logit - m_new), hi/lo exact split
        bf16x8 afH[2][2], afL[2][2];
#pragma unroll
        for (int mi = 0; mi < 2; ++mi) {
            const int kkm = kk0 + mi * 16;
            const float mk = mnew[kkm];
#pragma unroll
            for (int ks = 0; ks < 2; ++ks) {
                const int c0 = (ks * 8 + oct * 2) ^ lr;
                const int c1 = (ks * 8 + oct * 2 + 1) ^ lr;
                const float4 g0 = *(const float4*)(lgT + kkm * 256 + c0 * 16);
                const float4 g1 = *(const float4*)(lgT + kkm * 256 + c1 * 16);
                const int lb = l0 + ks * 32 + oct * 8;
                float e0 = (lb + 0 < len) ? __expf(g0.x - mk) : 0.f;
                float e1 = (lb + 1 < len) ? __expf(g0.y - mk) : 0.f;
                float e2 = (lb + 2 < len) ? __expf(g0.z - mk) : 0.f;
                float e3 = (lb + 3 < len) ? __expf(g0.w - mk) : 0.f;
                float e4 = (lb + 4 < len) ? __expf(g1.x - mk) : 0.f;
                float e5 = (lb + 5 < len) ? __expf(g1.y - mk) : 0.f;
                float e6 = (lb + 6 < len) ? __expf(g1.z - mk) : 0.f;
                float e7 = (lb + 7 < len) ? __expf(g1.w - mk) : 0.f;
                bf16x8 h, l2;
                h[0] = (bf16_t)e0; l2[0] = (bf16_t)(e0 - (float)h[0]);
                h[1] = (bf16_t)e1; l2[1] = (bf16_t)(e1 - (float)h[1]);
                h[2] = (bf16_t)e2; l2[2] = (bf16_t)(e2 - (float)h[2]);
                h[3] = (bf16_t)e3; l2[3] = (bf16_t)(e3 - (float)h[3]);
                h[4] = (bf16_t)e4; l2[4] = (bf16_t)(e4 - (float)h[4]);
                h[5] = (bf16_t)e5; l2[5] = (bf16_t)(e5 - (float)h[5]);
                h[6] = (bf16_t)e6; l2[6] = (bf16_t)(e6 - (float)h[6]);
                h[7] = (bf16_t)e7; l2[7] = (bf16_t)(e7 - (float)h[7]);
                afH[mi][ks] = h; afL[mi][ks] = l2;
            }
        }

        // ---- T14: prefetch next tile's stage half-0 (lands under AGG + bar0)
        if (tile + 1 < t1) LOADH(tile + 1, 0, pf);

        // ---- AGG MFMA: B from fT, reuse each B across 4 MFMAs
#pragma unroll
        for (int ks = 0; ks < 2; ++ks) {
#pragma unroll
            for (int nt = 0; nt < 16; ++nt) {
                const int d = dh * 256 + nt * 16 + lr;
                const int c = (ks * 4 + oct) ^ ((d ^ (d >> 3)) & 7);
                const bf16x8 bv = *(const bf16x8*)(fT + d * 128 + c * 16);
                acc[0][nt] = __builtin_amdgcn_mfma_f32_16x16x32_bf16(afH[0][ks], bv, acc[0][nt], 0, 0, 0);
                acc[0][nt] = __builtin_amdgcn_mfma_f32_16x16x32_bf16(afL[0][ks], bv, acc[0][nt], 0, 0, 0);
                acc[1][nt] = __builtin_amdgcn_mfma_f32_16x16x32_bf16(afH[1][ks], bv, acc[1][nt], 0, 0, 0);
                acc[1][nt] = __builtin_amdgcn_mfma_f32_16x16x32_bf16(afL[1][ks], bv, acc[1][nt], 0, 0, 0);
            }
        }
    }
#undef LOADH
#undef WRITEH

    // ---- epilogue: unnormalized partials + stats
    float* po = pO + (size_t)(b * NSPLIT + sp) * NK * ND;
#pragma unroll
    for (int mi = 0; mi < 2; ++mi)
#pragma unroll
        for (int nt = 0; nt < 16; ++nt) {
            const int d = dh * 256 + nt * 16 + lr;
#pragma unroll
            for (int r = 0; r < 4; ++r) {
                const int k = kh * 32 + mi * 16 + oct * 4 + r;
                po[(size_t)k * ND + d] = acc[mi][nt][r];
            }
        }
    if (t < 64) {
        mS[(size_t)(b * NSPLIT + sp) * 64 + t] = mrun[t];
        sS[(size_t)(b * NSPLIT + sp) * 64 + t] = srun[t];
    }
}

// ---------------- global stats -> per-split scale = exp(m_s - M) / S
__global__ void k_gstats(const float* __restrict__ mS, const float* __restrict__ sS,
                         float* __restrict__ scale) {
    const int b = blockIdx.x;
    const int k = threadIdx.x;  // 64
    float M = -1e30f;
#pragma unroll
    for (int s = 0; s < NSPLIT; ++s) M = fmaxf(M, mS[(b * NSPLIT + s) * 64 + k]);
    float S = 0.f;
#pragma unroll
    for (int s = 0; s < NSPLIT; ++s)
        S += sS[(b * NSPLIT + s) * 64 + k] * __expf(mS[(b * NSPLIT + s) * 64 + k] - M);
    const float inv = 1.f / S;
#pragma unroll
    for (int s = 0; s < NSPLIT; ++s)
        scale[(b * NSPLIT + s) * 64 + k] = __expf(mS[(b * NSPLIT + s) * 64 + k] - M) * inv;
}

// ---------------- combine: scaled partial sum, subtract centroid, min over k
__global__ __launch_bounds__(128) void k_combine(const float* __restrict__ pO,
                                                 const float* __restrict__ scale,
                                                 const float* __restrict__ centroids,
                                                 float* __restrict__ outun) {
    const int b = blockIdx.x >> 3;
    const int d = (blockIdx.x & 7) * 128 + threadIdx.x;  // 0..1023
    __shared__ float sc[NSPLIT][64];
    for (int i = threadIdx.x; i < NSPLIT * 64; i += 128)
        sc[i >> 6][i & 63] = scale[b * NSPLIT * 64 + i];
    __syncthreads();
    const float* pb = pO + (size_t)b * NSPLIT * NK * ND;
    float mn = 1e30f;
    for (int k = 0; k < NK; ++k) {
        float v = 0.f;
#pragma unroll
        for (int s = 0; s < NSPLIT; ++s)
            v += pb[(size_t)(s * NK + k) * ND + d] * sc[s][k];
        v -= centroids[(size_t)k * ND + d];
        mn = fminf(mn, v);
    }
    outun[(size_t)b * ND + d] = mn;
}

// ---------------- L2-normalize rows
__global__ __launch_bounds__(256) void k_norm(const float* __restrict__ outun,
                                              float* __restrict__ out) {
    const int b = blockIdx.x;
    const int t = threadIdx.x;
    float ss = 0.f;
    for (int d = t; d < ND; d += 256) {
        const float v = outun[(size_t)b * ND + d];
        ss += v * v;
    }
#pragma unroll
    for (int off = 32; off > 0; off >>= 1) ss += __shfl_down(ss, off);
    __shared__ float red[4];
    if ((t & 63) == 0) red[t >> 6] = ss;
    __syncthreads();
    const float tot = red[0] + red[1] + red[2] + red[3];
    const float inv = 1.0f / fmaxf(sqrtf(tot), 1e-12f);
    for (int d = t; d < ND; d += 256) out[(size_t)b * ND + d] = outun[(size_t)b * ND + d] * inv;
}

extern "C" void kernel_launch(void* const* d_in, const int* in_sizes, int n_in,
                              void* d_out, int out_size, void* d_ws, size_t ws_size,
                              hipStream_t stream) {
    const float* feats     = (const float*)d_in[0];
    const int*   lens      = (const int*)d_in[1];
    const float* W         = (const float*)d_in[2];
    const float* bias      = (const float*)d_in[3];
    const float* centroids = (const float*)d_in[4];
    float* out = (float*)d_out;

    char* ws = (char*)d_ws;
    size_t off = 0;
    bf16_t* Wb   = (bf16_t*)(ws + off); off += (size_t)NK * ND * sizeof(bf16_t);
    float* pO    = (float*)(ws + off);  off += (size_t)NB * NSPLIT * NK * ND * sizeof(float); // 134 MB
    float* mS    = (float*)(ws + off);  off += (size_t)NB * NSPLIT * 64 * sizeof(float);
    float* sS    = (float*)(ws + off);  off += (size_t)NB * NSPLIT * 64 * sizeof(float);
    float* scale = (float*)(ws + off);  off += (size_t)NB * NSPLIT * 64 * sizeof(float);
    float* outun = (float*)(ws + off);  off += (size_t)NB * ND * sizeof(float);

    const size_t LDSB = 152832;  // fT 128K + lgT 16K + red/stats

    k_convw<<<NK * ND / 1024, 256, 0, stream>>>(W, Wb);
    k_fused<<<NB * NSPLIT, 512, LDSB, stream>>>(feats, Wb, bias, lens, pO, mS, sS);
    k_gstats<<<NB, 64, 0, stream>>>(mS, sS, scale);
    k_combine<<<NB * 8, 128, 0, stream>>>(pO, scale, centroids, outun);
    k_norm<<<NB, 256, 0, stream>>>(outun, out);
}

// Round 14
// 281.657 us; speedup vs baseline: 2.2405x; 2.2405x over previous
//
#include <hip/hip_runtime.h>
#include <math.h>

#define NB 32
#define NL 4096
#define ND 1024
#define NK 64
#define DTILE 128
#define S_SPLIT 4

typedef __bf16 bf16_t;
typedef __bf16 bf16x8 __attribute__((ext_vector_type(8)));
typedef __bf16 bf16x4 __attribute__((ext_vector_type(4)));
typedef float f32x4_t __attribute__((ext_vector_type(4)));

// ---------------- Kernel 0: W fp32 -> bf16
__global__ __launch_bounds__(256) void k_convw(const float* __restrict__ W,
                                               bf16_t* __restrict__ Wb) {
    const int i = (blockIdx.x * 256 + threadIdx.x) * 4;
    const float4 v = *(const float4*)(W + i);
    bf16x4 o;
    o[0] = (bf16_t)v.x; o[1] = (bf16_t)v.y; o[2] = (bf16_t)v.z; o[3] = (bf16_t)v.w;
    *(bf16x4*)(Wb + i) = o;
}

// ---------------- Kernel 1: logits (bf16 MFMA), 64 l per wave, 256 l per block
// Writes logitsT[b][k][l] with float4 stores; fused per-256-l-chunk softmax stats.
// Verified conv: A lane(lr,oct): m=lr, c=oct*8+j; B: n=lr, c=oct*8+j;
// C: col(n)=lane&15, row(m)=oct*4+reg.
__global__ __launch_bounds__(256, 2) void k_logits(const float* __restrict__ feats,
                                                   const bf16_t* __restrict__ Wb,
                                                   const float* __restrict__ bias,
                                                   const int* __restrict__ lens,
                                                   float* __restrict__ logitsT,
                                                   float* __restrict__ pmax,
                                                   float* __restrict__ psum) {
    const int bid = blockIdx.x;
    const int b = bid >> 4;
    const int chunk = bid & 15;
    const int l0 = chunk << 8;       // 256 l per block
    const int len = lens[b];
    if (l0 >= len) return;   // rows >= len never read downstream
    const int t = threadIdx.x;
    const int w = t >> 6;
    const int lane = t & 63;
    const int lr = lane & 15;
    const int oct = lane >> 4;
    const int lw = l0 + w * 64;      // wave's l-base (4 m-tiles of 16)
    const float* fp = feats + ((size_t)b * NL + lw + lr) * ND + oct * 8;

    f32x4_t acc[4][4];  // [mt][j]
#pragma unroll
    for (int m = 0; m < 4; ++m)
#pragma unroll
        for (int j = 0; j < 4; ++j) acc[m][j] = (f32x4_t){0.f, 0.f, 0.f, 0.f};

#pragma unroll 2
    for (int kk = 0; kk < 32; ++kk) {
        const int d = kk * 32;
        bf16x8 af[4];
#pragma unroll
        for (int mt = 0; mt < 4; ++mt) {
            const float4 a0 = *(const float4*)(fp + (size_t)mt * 16 * ND + d);
            const float4 a1 = *(const float4*)(fp + (size_t)mt * 16 * ND + d + 4);
            af[mt][0] = (bf16_t)a0.x; af[mt][1] = (bf16_t)a0.y;
            af[mt][2] = (bf16_t)a0.z; af[mt][3] = (bf16_t)a0.w;
            af[mt][4] = (bf16_t)a1.x; af[mt][5] = (bf16_t)a1.y;
            af[mt][6] = (bf16_t)a1.z; af[mt][7] = (bf16_t)a1.w;
        }
#pragma unroll
        for (int j = 0; j < 4; ++j) {
            const bf16x8 bf = *(const bf16x8*)(Wb + (size_t)(j * 16 + lr) * ND + d + oct * 8);
#pragma unroll
            for (int mt = 0; mt < 4; ++mt)
                acc[mt][j] = __builtin_amdgcn_mfma_f32_16x16x32_bf16(af[mt], bf, acc[mt][j], 0, 0, 0);
        }
    }
    float vals[4][4][4];
#pragma unroll
    for (int mt = 0; mt < 4; ++mt)
#pragma unroll
        for (int j = 0; j < 4; ++j) {
            const int k = j * 16 + lr;
            const float bs = bias[k];
#pragma unroll
            for (int r = 0; r < 4; ++r) vals[mt][j][r] = acc[mt][j][r] + bs;
            const int lb = lw + mt * 16 + oct * 4;
            float4 st = make_float4(vals[mt][j][0], vals[mt][j][1], vals[mt][j][2], vals[mt][j][3]);
            *(float4*)(logitsT + ((size_t)b * NK + k) * NL + lb) = st;
        }
    // fused partial softmax stats for this 256-l chunk (16 slots per k)
    __shared__ float red[64][17];
    __shared__ float bm[64];
    const int slot = w * 4 + oct;
#pragma unroll
    for (int j = 0; j < 4; ++j) {
        float vm = -1e30f;
#pragma unroll
        for (int mt = 0; mt < 4; ++mt) {
            const int lbase = lw + mt * 16 + oct * 4;
#pragma unroll
            for (int r = 0; r < 4; ++r)
                if (lbase + r < len) vm = fmaxf(vm, vals[mt][j][r]);
        }
        red[j * 16 + lr][slot] = vm;
    }
    __syncthreads();
    if (t < 64) {
        float m = -1e30f;
#pragma unroll
        for (int q = 0; q < 16; ++q) m = fmaxf(m, red[t][q]);
        bm[t] = m;
    }
    __syncthreads();
#pragma unroll
    for (int j = 0; j < 4; ++j) {
        const float mk = bm[j * 16 + lr];
        float sj = 0.f;
#pragma unroll
        for (int mt = 0; mt < 4; ++mt) {
            const int lbase = lw + mt * 16 + oct * 4;
#pragma unroll
            for (int r = 0; r < 4; ++r)
                if (lbase + r < len) sj += __expf(vals[mt][j][r] - mk);
        }
        red[j * 16 + lr][slot] = sj;
    }
    __syncthreads();
    if (t < 64) {
        float ssum = 0.f;
#pragma unroll
        for (int q = 0; q < 16; ++q) ssum += red[t][q];
        pmax[((size_t)b * 16 + chunk) * 64 + t] = bm[t];
        psum[((size_t)b * 16 + chunk) * 64 + t] = ssum;
    }
}

// ---------------- Kernel 2: combine chunk stats -> mbuf2 = m + ln(s) per (b,k)
__global__ void k_sm2(const float* __restrict__ pmax, const float* __restrict__ psum,
                      const int* __restrict__ lens,
                      float* __restrict__ mbuf2) {
    const int b = blockIdx.x;
    const int k = threadIdx.x;  // 64 threads
    const int nc = (lens[b] + 255) >> 8;
    float m = -1e30f;
    for (int c = 0; c < nc; ++c) m = fmaxf(m, pmax[((size_t)b * 16 + c) * 64 + k]);
    float s = 0.f;
    for (int c = 0; c < nc; ++c)
        s += psum[((size_t)b * 16 + c) * 64 + k] * __expf(pmax[((size_t)b * 16 + c) * 64 + k] - m);
    mbuf2[b * 64 + k] = m + logf(s);
}

// ---------------- Kernel 3: bf16-MFMA aggregation (exact-a x bf16-f)
// a split hi/lo in registers (a = aH+aL exact); f rounded to bf16 in LDS.
// acc += aH*fH + aL*fH == a*fH with each product exact in fp32 accum.
// Wave partition: (kh = w&1: 32 k) x (dh = w>>1: 64 d).
__global__ __launch_bounds__(256, 3) void k_aggregate(const float* __restrict__ feats,
                                                      const float* __restrict__ logitsT,
                                                      const int* __restrict__ lens,
                                                      const float* __restrict__ mbuf2,
                                                      float* __restrict__ pO) {
    const int bid = blockIdx.x;
    const int s  = bid & 3;
    const int dc = (bid >> 2) & 7;
    const int b  = bid >> 5;
    const int d0 = dc * DTILE;
    const int t = threadIdx.x;
    const int kh = (t >> 6) & 1;
    const int dh = t >> 7;
    const int lane = t & 63;
    const int lr = lane & 15;
    const int oct = lane >> 4;
    const int len = lens[b];
    const int nT = (len + 63) >> 6;
    const int t0 = (nT * s) >> 2;
    const int t1 = (nT * (s + 1)) >> 2;

    __shared__ char fH[16 * 1024];   // fT[128 d][64 l] bf16, chunk-XOR swizzled

    const int kk0 = kh * 32 + lr;    // A m-row (k) for mt=0; mt=1 adds 16
    const float ms0 = mbuf2[b * 64 + kk0];
    const float ms1 = mbuf2[b * 64 + kk0 + 16];
    const float* lg0 = logitsT + ((size_t)b * NK + kk0) * NL;
    const float* lg1 = lg0 + (size_t)16 * NL;

    // f-staging constants: thread owns rows lf0+{0..3} (x2 phases), cols c4..c4+3
    const int c4 = (t & 31) * 4;
    const int lf0 = (t >> 5) * 4;

    f32x4_t acc[2][4];  // [mt][n]
#pragma unroll
    for (int m = 0; m < 2; ++m)
#pragma unroll
        for (int n = 0; n < 4; ++n) acc[m][n] = (f32x4_t){0.f, 0.f, 0.f, 0.f};

    float4 pf[2][4];     // [phase][row]: prefetched f rows (T14)

#define LOADF(tile_)                                                                     \
    {                                                                                    \
        const int lb_ = (tile_) * 64;                                                    \
        _Pragma("unroll")                                                                \
        for (int p_ = 0; p_ < 2; ++p_) {                                                 \
            _Pragma("unroll")                                                            \
            for (int i_ = 0; i_ < 4; ++i_)                                               \
                pf[p_][i_] = *(const float4*)(feats +                                    \
                    ((size_t)b * NL + lb_ + p_ * 32 + lf0 + i_) * ND + d0 + c4);         \
        }                                                                                \
    }

    if (t0 < t1) LOADF(t0);

    for (int tile = t0; tile < t1; ++tile) {
        const int l0 = tile * 64;
        // ---- load this tile's logits runs + build A fragments in registers
        bf16x8 afH[2][2], afL[2][2];   // [mt][ks]
#pragma unroll
        for (int mt = 0; mt < 2; ++mt) {
            const float* lg = mt ? lg1 : lg0;
            const float msk = mt ? ms1 : ms0;
            float4 g[4];
            g[0] = *(const float4*)(lg + l0 + oct * 8);
            g[1] = *(const float4*)(lg + l0 + oct * 8 + 4);
            g[2] = *(const float4*)(lg + l0 + 32 + oct * 8);
            g[3] = *(const float4*)(lg + l0 + 32 + oct * 8 + 4);
#pragma unroll
            for (int ks = 0; ks < 2; ++ks) {
#pragma unroll
                for (int h = 0; h < 2; ++h) {
                    const float4 v = g[ks * 2 + h];
                    const int lbase = l0 + ks * 32 + oct * 8 + h * 4;
                    float av[4];
                    av[0] = (lbase + 0 < len) ? __expf(v.x - msk) : 0.f;
                    av[1] = (lbase + 1 < len) ? __expf(v.y - msk) : 0.f;
                    av[2] = (lbase + 2 < len) ? __expf(v.z - msk) : 0.f;
                    av[3] = (lbase + 3 < len) ? __expf(v.w - msk) : 0.f;
#pragma unroll
                    for (int c = 0; c < 4; ++c) {
                        const bf16_t hi = (bf16_t)av[c];
                        afH[mt][ks][h * 4 + c] = hi;
                        afL[mt][ks][h * 4 + c] = (bf16_t)(av[c] - (float)hi);
                    }
                }
            }
        }
        __syncthreads();   // all waves done reading fH of previous tile
        // ---- stage f^T (bf16) from pf: 4x4 register micro-transpose
#pragma unroll
        for (int p = 0; p < 2; ++p) {
            const int l4 = p * 32 + lf0;
#pragma unroll
            for (int j = 0; j < 4; ++j) {
                const int d = c4 + j;
                bf16x4 hi;
                hi[0] = (bf16_t)(&pf[p][0].x)[j];
                hi[1] = (bf16_t)(&pf[p][1].x)[j];
                hi[2] = (bf16_t)(&pf[p][2].x)[j];
                hi[3] = (bf16_t)(&pf[p][3].x)[j];
                const int chunk = (l4 >> 3) ^ ((d ^ (d >> 3)) & 7);
                const int off = d * 128 + (chunk << 4) + (l4 & 7) * 2;
                *(bf16x4*)(fH + off) = hi;
            }
        }
        // ---- T14: issue next tile's f loads (in flight across barrier + MFMA)
        if (tile + 1 < t1) LOADF(tile + 1);
        __syncthreads();   // fH ready
        // ---- MFMA: wave owns k in [kh*32, +32), d in [dh*64, +64)
#pragma unroll
        for (int ks = 0; ks < 2; ++ks) {
            const int cbase = ks * 4 + oct;  // chunk of contraction l = ks*32 + oct*8
            bf16x8 bfv[4];
#pragma unroll
            for (int n = 0; n < 4; ++n) {
                const int d = dh * 64 + n * 16 + lr;
                const int foff = d * 128 + ((cbase ^ ((d ^ (d >> 3)) & 7)) << 4);
                bfv[n] = *(const bf16x8*)(fH + foff);
            }
#pragma unroll
            for (int mt = 0; mt < 2; ++mt)
#pragma unroll
                for (int n = 0; n < 4; ++n) {
                    acc[mt][n] = __builtin_amdgcn_mfma_f32_16x16x32_bf16(afH[mt][ks], bfv[n], acc[mt][n], 0, 0, 0);
                    acc[mt][n] = __builtin_amdgcn_mfma_f32_16x16x32_bf16(afL[mt][ks], bfv[n], acc[mt][n], 0, 0, 0);
                }
        }
    }
#undef LOADF
    // write fp32 partials: pO[b][dc][s][k][DTILE]; C: row(m=k)=oct*4+r, col=lr
    float* po = pO + ((size_t)((b * 8 + dc) * S_SPLIT + s)) * (NK * DTILE);
#pragma unroll
    for (int mt = 0; mt < 2; ++mt)
#pragma unroll
        for (int n = 0; n < 4; ++n) {
#pragma unroll
            for (int r = 0; r < 4; ++r) {
                const int k = kh * 32 + mt * 16 + oct * 4 + r;
                po[k * DTILE + dh * 64 + n * 16 + lr] = acc[mt][n][r];
            }
        }
}

// ---------------- Kernel 4: sum S_SPLIT partials, subtract centroid, min over k
__global__ __launch_bounds__(128) void k_combine(const float* __restrict__ pO,
                                                 const float* __restrict__ centroids,
                                                 float* __restrict__ outun) {
    const int b = blockIdx.x >> 3;
    const int d = (blockIdx.x & 7) * 128 + threadIdx.x;  // 0..1023
    const int dc = d >> 7;
    const int dl = d & 127;
    const float* base = pO + ((size_t)(b * 8 + dc)) * S_SPLIT * NK * DTILE;
    float mn = 1e30f;
    for (int k = 0; k < NK; ++k) {
        float v = 0.f;
#pragma unroll
        for (int s = 0; s < S_SPLIT; ++s) v += base[(size_t)(s * NK + k) * DTILE + dl];
        v -= centroids[(size_t)k * ND + d];
        mn = fminf(mn, v);
    }
    outun[(size_t)b * ND + d] = mn;
}

// ---------------- Kernel 5: L2-normalize rows
__global__ __launch_bounds__(256) void k_norm(const float* __restrict__ outun,
                                              float* __restrict__ out) {
    const int b = blockIdx.x;
    const int t = threadIdx.x;
    float ss = 0.f;
    for (int d = t; d < ND; d += 256) {
        const float v = outun[(size_t)b * ND + d];
        ss += v * v;
    }
#pragma unroll
    for (int off = 32; off > 0; off >>= 1) ss += __shfl_down(ss, off);
    __shared__ float red[4];
    if ((t & 63) == 0) red[t >> 6] = ss;
    __syncthreads();
    const float tot = red[0] + red[1] + red[2] + red[3];
    const float inv = 1.0f / fmaxf(sqrtf(tot), 1e-12f);
    for (int d = t; d < ND; d += 256) out[(size_t)b * ND + d] = outun[(size_t)b * ND + d] * inv;
}

extern "C" void kernel_launch(void* const* d_in, const int* in_sizes, int n_in,
                              void* d_out, int out_size, void* d_ws, size_t ws_size,
                              hipStream_t stream) {
    const float* feats     = (const float*)d_in[0];
    const int*   lens      = (const int*)d_in[1];
    const float* W         = (const float*)d_in[2];
    const float* bias      = (const float*)d_in[3];
    const float* centroids = (const float*)d_in[4];
    float* out = (float*)d_out;

    char* ws = (char*)d_ws;
    size_t off = 0;
    bf16_t* Wb     = (bf16_t*)(ws + off); off += (size_t)NK * ND * sizeof(bf16_t);
    float* logitsT = (float*)(ws + off);  off += (size_t)NB * NL * NK * sizeof(float);
    float* pmax    = (float*)(ws + off);  off += (size_t)NB * 16 * NK * sizeof(float);
    float* psum    = (float*)(ws + off);  off += (size_t)NB * 16 * NK * sizeof(float);
    float* mbuf2   = (float*)(ws + off);  off += (size_t)NB * NK * sizeof(float);
    float* outun   = (float*)(ws + off);  off += (size_t)NB * ND * sizeof(float);
    float* pO      = (float*)(ws + off);  // 32*8*4*64*128*4 = 33.6 MB

    k_convw<<<NK * ND / 1024, 256, 0, stream>>>(W, Wb);
    k_logits<<<NB * (NL / 256), 256, 0, stream>>>(feats, Wb, bias, lens, logitsT, pmax, psum);
    k_sm2<<<NB, 64, 0, stream>>>(pmax, psum, lens, mbuf2);
    k_aggregate<<<NB * 8 * S_SPLIT, 256, 0, stream>>>(feats, logitsT, lens, mbuf2, pO);
    k_combine<<<NB * 8, 128, 0, stream>>>(pO, centroids, outun);
    k_norm<<<NB, 256, 0, stream>>>(outun, out);
}